// Round 3
// baseline (67.417 us; speedup 1.0000x reference)
//
#include <hip/hip_runtime.h>
#include <cstdint>

#define HD __device__ __forceinline__

constexpr int B = 4, N = 8192, H = 128, W = 128, K = 8;
constexpr float BIGF = 1e10f;
constexpr int TILES_PER_IMG = 256;   // 16x16 tiles of 8x8 pixels
constexpr int NTILES = B * TILES_PER_IMG;
constexpr int LCAP = 256;            // LDS candidate list capacity
constexpr int FLUSH = 128;           // process list when it exceeds this

HD bool keyless(float z1, int i1, float z2, int i2) {
    return (z1 < z2) || ((z1 == z2) && (i1 < i2));
}

// branchless unrolled insert into ascending (z,idx)-sorted top-K registers.
// Caller guarantees keyless(nz,ni, zk[K-1],ik[K-1]).
HD void insert_topk(float nz, int ni, float nd,
                    float (&zk)[K], int (&ik)[K], float (&dk)[K]) {
    bool lt[K];
#pragma unroll
    for (int j = 0; j < K; ++j) lt[j] = keyless(nz, ni, zk[j], ik[j]);
#pragma unroll
    for (int j = K - 1; j >= 1; --j) {
        if (lt[j]) {
            if (lt[j - 1]) { zk[j] = zk[j - 1]; ik[j] = ik[j - 1]; dk[j] = dk[j - 1]; }
            else           { zk[j] = nz;        ik[j] = ni;        dk[j] = nd; }
        }
    }
    if (lt[0]) { zk[0] = nz; ik[0] = ni; dk[0] = nd; }
}

HD void transform_point(const float* __restrict__ w2v, const float* __restrict__ p2n,
                        float x, float y, float z,
                        float& xn, float& yn, float& zn) {
    float pv[4];
#pragma unroll
    for (int j = 0; j < 4; ++j)
        pv[j] = x * w2v[0 * 4 + j] + y * w2v[1 * 4 + j] +
                z * w2v[2 * 4 + j] + 1.0f * w2v[3 * 4 + j];
    float viewz = pv[2];
    float q[4];
#pragma unroll
    for (int j = 0; j < 4; ++j)
        q[j] = pv[0] * p2n[0 * 4 + j] + pv[1] * p2n[1 * 4 + j] +
               pv[2] * p2n[2 * 4 + j] + pv[3] * p2n[3 * 4 + j];
    float wq = q[3];
    float sgn = (wq >= 0.0f) ? 1.0f : -1.0f;
    float denom = sgn * fmaxf(fabsf(wq), 1e-6f);
    xn = q[0] / denom;
    yn = q[1] / denom;
    zn = viewz;
}

HD void process_candidate(float4 p, float px, float py, float r2,
                          float (&zk)[K], int (&ik)[K], float (&dk)[K]) {
    float dx = p.x - px, dy = p.y - py;
    float d2 = __fadd_rn(__fmul_rn(dx, dx), __fmul_rn(dy, dy));
    int pi = __float_as_int(p.w);
    if ((d2 <= r2) && (p.z > 0.0f) && keyless(p.z, pi, zk[K - 1], ik[K - 1]))
        insert_topk(p.z, pi, d2, zk, ik, dk);
}

HD void write_out(float* __restrict__ out, int b, int h, int w,
                  const float (&zk)[K], const int (&ik)[K], const float (&dk)[K]) {
    const size_t S = (size_t)B * H * W * K;
    size_t pix = (((size_t)b * H + h) * W + w) * K;
    float fi[K], fz[K], fd[K];
#pragma unroll
    for (int j = 0; j < K; ++j) {
        bool valid = zk[j] < 0.5f * BIGF;
        fi[j] = valid ? (float)ik[j] : -1.0f;
        fz[j] = valid ? zk[j] : -1.0f;
        fd[j] = valid ? dk[j] : -1.0f;
    }
    float4* o0 = reinterpret_cast<float4*>(out + pix);
    float4* o1 = reinterpret_cast<float4*>(out + S + pix);
    float4* o2 = reinterpret_cast<float4*>(out + 2 * S + pix);
    float4* o3 = reinterpret_cast<float4*>(out + 3 * S + pix);
    o0[0] = make_float4(fi[0], fi[1], fi[2], fi[3]);
    o0[1] = make_float4(fi[4], fi[5], fi[6], fi[7]);
    o1[0] = make_float4(fz[0], fz[1], fz[2], fz[3]);
    o1[1] = make_float4(fz[4], fz[5], fz[6], fz[7]);
    o2[0] = make_float4(fi[0], fi[1], fi[2], fi[3]);
    o2[1] = make_float4(fi[4], fi[5], fi[6], fi[7]);
    o3[0] = make_float4(fd[0], fd[1], fd[2], fd[3]);
    o3[1] = make_float4(fd[4], fd[5], fd[6], fd[7]);
}

// ---------------- fully fused: one block = one 8x8-pixel tile ----------------
// Each block re-transforms its batch's 8192 points (cheap, cache-hot),
// ballot-compacts the ~56 tile hits into an LDS list, then runs the exact
// per-pixel top-8 selection. Single wave per block: no atomics, no races,
// deterministic order.
__global__ __launch_bounds__(64) void fused_raster_kernel(
    const float* __restrict__ points, const float* __restrict__ w2v,
    const float* __restrict__ p2n, float* __restrict__ out) {
    int t = blockIdx.x;              // 0..NTILES-1
    int b = t >> 8;                  // 256 tiles per image
    int ti = t & 255;
    int ty = ti >> 4, tx = ti & 15;
    int lane = threadIdx.x;          // 0..63

    int h = ty * 8 + (lane >> 3);
    int w = tx * 8 + (lane & 7);
    float px = 1.0f - (2.0f * (float)w + 1.0f) / 128.0f;
    float py = 1.0f - (2.0f * (float)h + 1.0f) / 128.0f;
    const float r2 = (float)(0.02 * 0.02);
    const float rb = 0.0201f;        // conservative bbox margin (> RADIUS)

    // tile pixel-center bounds in NDC (px decreases with w)
    float pxmax = 1.0f - (float)(16 * tx + 1) / 128.0f;
    float pxmin = pxmax - 14.0f / 128.0f;
    float pymax = 1.0f - (float)(16 * ty + 1) / 128.0f;
    float pymin = pymax - 14.0f / 128.0f;
    float xlo = pxmin - rb, xhi = pxmax + rb;
    float ylo = pymin - rb, yhi = pymax + rb;

    __shared__ float4 list[LCAP];

    float zk[K]; int ik[K]; float dk[K];
#pragma unroll
    for (int j = 0; j < K; ++j) { zk[j] = BIGF; ik[j] = 0x7fffffff; dk[j] = 0.0f; }

    const float* pbase = points + (size_t)b * N * 3;
    const unsigned long long lmask_lt = (1ull << lane) - 1ull;
    int base = 0;                    // wave-uniform list count

    for (int c = 0; c < N; c += 128) {   // 2 points per lane per iter (ILP)
        int n0 = c + lane, n1 = c + 64 + lane;
        float x0 = pbase[n0 * 3 + 0], y0 = pbase[n0 * 3 + 1], z0 = pbase[n0 * 3 + 2];
        float x1 = pbase[n1 * 3 + 0], y1 = pbase[n1 * 3 + 1], z1 = pbase[n1 * 3 + 2];
        float xn0, yn0, zn0, xn1, yn1, zn1;
        transform_point(w2v, p2n, x0, y0, z0, xn0, yn0, zn0);
        transform_point(w2v, p2n, x1, y1, z1, xn1, yn1, zn1);
        bool hit0 = (zn0 > 0.0f) && (xn0 >= xlo) && (xn0 <= xhi) && (yn0 >= ylo) && (yn0 <= yhi);
        bool hit1 = (zn1 > 0.0f) && (xn1 >= xlo) && (xn1 <= xhi) && (yn1 >= ylo) && (yn1 <= yhi);

        unsigned long long m0 = __ballot(hit0);
        if (hit0) list[base + (int)__popcll(m0 & lmask_lt)] =
            make_float4(xn0, yn0, zn0, __int_as_float(n0));
        base += (int)__popcll(m0);
        unsigned long long m1 = __ballot(hit1);
        if (hit1) list[base + (int)__popcll(m1 & lmask_lt)] =
            make_float4(xn1, yn1, zn1, __int_as_float(n1));
        base += (int)__popcll(m1);

        if (base > FLUSH) {              // uniform condition, 1-wave block
            __syncthreads();
            for (int e = 0; e < base; ++e)
                process_candidate(list[e], px, py, r2, zk, ik, dk);
            __syncthreads();
            base = 0;
        }
    }
    __syncthreads();
    for (int e = 0; e < base; ++e)
        process_candidate(list[e], px, py, r2, zk, ik, dk);

    write_out(out, b, h, w, zk, ik, dk);
}

extern "C" void kernel_launch(void* const* d_in, const int* in_sizes, int n_in,
                              void* d_out, int out_size, void* d_ws, size_t ws_size,
                              hipStream_t stream) {
    const float* points = (const float*)d_in[0];
    const float* w2v    = (const float*)d_in[1];
    const float* p2n    = (const float*)d_in[2];
    float* out = (float*)d_out;
    (void)d_ws; (void)ws_size;

    fused_raster_kernel<<<NTILES, 64, 0, stream>>>(points, w2v, p2n, out);
}

// Round 4
// 29.017 us; speedup vs baseline: 2.3234x; 2.3234x over previous
//
#include <hip/hip_runtime.h>
#include <cstdint>

#define HD __device__ __forceinline__

constexpr int B = 4, N = 8192, H = 128, W = 128, K = 8;
constexpr float BIGF = 1e10f;
constexpr int TOTPIX = B * H * W;   // 65536
constexpr int CAPP = 32;            // per-pixel list capacity (E[hits]~2.6)

HD bool keyless(float z1, int i1, float z2, int i2) {
    return (z1 < z2) || ((z1 == z2) && (i1 < i2));
}

// branchless unrolled insert into ascending (z,idx)-sorted top-K registers.
// Caller guarantees keyless(nz,ni, zk[K-1],ik[K-1]).
HD void insert_topk(float nz, int ni, float nd,
                    float (&zk)[K], int (&ik)[K], float (&dk)[K]) {
    bool lt[K];
#pragma unroll
    for (int j = 0; j < K; ++j) lt[j] = keyless(nz, ni, zk[j], ik[j]);
#pragma unroll
    for (int j = K - 1; j >= 1; --j) {
        if (lt[j]) {
            if (lt[j - 1]) { zk[j] = zk[j - 1]; ik[j] = ik[j - 1]; dk[j] = dk[j - 1]; }
            else           { zk[j] = nz;        ik[j] = ni;        dk[j] = nd; }
        }
    }
    if (lt[0]) { zk[0] = nz; ik[0] = ni; dk[0] = nd; }
}

HD void transform_point(const float* __restrict__ w2v, const float* __restrict__ p2n,
                        float x, float y, float z,
                        float& xn, float& yn, float& zn) {
    float pv[4];
#pragma unroll
    for (int j = 0; j < 4; ++j)
        pv[j] = x * w2v[0 * 4 + j] + y * w2v[1 * 4 + j] +
                z * w2v[2 * 4 + j] + 1.0f * w2v[3 * 4 + j];
    float viewz = pv[2];
    float q[4];
#pragma unroll
    for (int j = 0; j < 4; ++j)
        q[j] = pv[0] * p2n[0 * 4 + j] + pv[1] * p2n[1 * 4 + j] +
               pv[2] * p2n[2 * 4 + j] + pv[3] * p2n[3 * 4 + j];
    float wq = q[3];
    float sgn = (wq >= 0.0f) ? 1.0f : -1.0f;
    float denom = sgn * fmaxf(fabsf(wq), 1e-6f);
    xn = q[0] / denom;
    yn = q[1] / denom;
    zn = viewz;
}

HD void write_out(float* __restrict__ out, int pix,
                  const float (&zk)[K], const int (&ik)[K], const float (&dk)[K]) {
    const size_t S = (size_t)TOTPIX * K;
    size_t off = (size_t)pix * K;
    float fi[K], fz[K], fd[K];
#pragma unroll
    for (int j = 0; j < K; ++j) {
        bool valid = zk[j] < 0.5f * BIGF;
        fi[j] = valid ? (float)ik[j] : -1.0f;
        fz[j] = valid ? zk[j] : -1.0f;
        fd[j] = valid ? dk[j] : -1.0f;
    }
    float4* o0 = reinterpret_cast<float4*>(out + off);
    float4* o1 = reinterpret_cast<float4*>(out + S + off);
    float4* o2 = reinterpret_cast<float4*>(out + 2 * S + off);
    float4* o3 = reinterpret_cast<float4*>(out + 3 * S + off);
    o0[0] = make_float4(fi[0], fi[1], fi[2], fi[3]);
    o0[1] = make_float4(fi[4], fi[5], fi[6], fi[7]);
    o1[0] = make_float4(fz[0], fz[1], fz[2], fz[3]);
    o1[1] = make_float4(fz[4], fz[5], fz[6], fz[7]);
    o2[0] = make_float4(fi[0], fi[1], fi[2], fi[3]);
    o2[1] = make_float4(fi[4], fi[5], fi[6], fi[7]);
    o3[0] = make_float4(fd[0], fd[1], fd[2], fd[3]);
    o3[1] = make_float4(fd[4], fd[5], fd[6], fd[7]);
}

// ---------------- phase 0: zero per-pixel counters (256 KB) ----------------
__global__ __launch_bounds__(256) void zero_cnt_kernel(int4* __restrict__ cnt4) {
    int i = blockIdx.x * 256 + threadIdx.x;   // 64 blocks -> 16384 int4 = 64Ki ints
    cnt4[i] = make_int4(0, 0, 0, 0);
}

// ---------------- phase 1: transform + exact per-pixel binning -------------
// One thread per point. Stores only TRUE hits (d2 <= r2, z > 0) as
// (z, d2, idx) into per-pixel lists, layout [slot][pixel] for coalesced
// phase-2 reads. List order is nondeterministic; selection in phase 2 is by
// the total order (z, idx) -> deterministic output.
__global__ __launch_bounds__(128) void bin_pixels_kernel(
    const float* __restrict__ points, const float* __restrict__ w2v,
    const float* __restrict__ p2n, int* __restrict__ cnt,
    float4* __restrict__ entries) {
    int gid = blockIdx.x * 128 + threadIdx.x;   // 0..B*N-1
    int b = gid >> 13;           // N = 8192
    int n = gid & (N - 1);
    float x = points[(size_t)gid * 3 + 0];
    float y = points[(size_t)gid * 3 + 1];
    float z = points[(size_t)gid * 3 + 2];
    float xn, yn, zn;
    transform_point(w2v, p2n, x, y, z, xn, yn, zn);
    if (!(zn > 0.0f)) return;

    const float rb = 0.0201f;    // conservative bbox; exact d2 filter below
    const float r2 = (float)(0.02 * 0.02);
    int wmin = (int)ceilf(((1.0f - xn) - rb) * 64.0f - 0.5f);
    int wmax = (int)floorf(((1.0f - xn) + rb) * 64.0f - 0.5f);
    int hmin = (int)ceilf(((1.0f - yn) - rb) * 64.0f - 0.5f);
    int hmax = (int)floorf(((1.0f - yn) + rb) * 64.0f - 0.5f);
    wmin = max(wmin, 0); wmax = min(wmax, W - 1);
    hmin = max(hmin, 0); hmax = min(hmax, H - 1);

    for (int h = hmin; h <= hmax; ++h) {
        float py = 1.0f - (2.0f * (float)h + 1.0f) / 128.0f;
        float dy = yn - py;
        float dy2 = __fmul_rn(dy, dy);
        for (int w = wmin; w <= wmax; ++w) {
            float px = 1.0f - (2.0f * (float)w + 1.0f) / 128.0f;
            float dx = xn - px;
            float d2 = __fadd_rn(__fmul_rn(dx, dx), dy2);
            if (d2 <= r2) {
                int pix = (b << 14) + (h << 7) + w;
                int pos = atomicAdd(&cnt[pix], 1);
                if (pos < CAPP)
                    entries[(size_t)pos * TOTPIX + pix] =
                        make_float4(zn, d2, __int_as_float(n), 0.0f);
            }
        }
    }
}

// ---------------- phase 2: per-pixel top-8 selection ------------------------
__global__ __launch_bounds__(256) void select_kernel(
    const int* __restrict__ cnt, const float4* __restrict__ entries,
    float* __restrict__ out) {
    int pix = blockIdx.x * 256 + threadIdx.x;   // 0..TOTPIX-1
    int c = cnt[pix];
    if (c > CAPP) c = CAPP;

    float zk[K]; int ik[K]; float dk[K];
#pragma unroll
    for (int j = 0; j < K; ++j) { zk[j] = BIGF; ik[j] = 0x7fffffff; dk[j] = 0.0f; }

    for (int j = 0; j < c; ++j) {
        float4 e = entries[(size_t)j * TOTPIX + pix];
        int pi = __float_as_int(e.z);
        if (keyless(e.x, pi, zk[K - 1], ik[K - 1]))
            insert_topk(e.x, pi, e.y, zk, ik, dk);
    }
    write_out(out, pix, zk, ik, dk);
}

// ---------------- fallback: brute force (no workspace needed) ----------------
HD void process_candidate(float4 p, float px, float py, float r2,
                          float (&zk)[K], int (&ik)[K], float (&dk)[K]) {
    float dx = p.x - px, dy = p.y - py;
    float d2 = __fadd_rn(__fmul_rn(dx, dx), __fmul_rn(dy, dy));
    int pi = __float_as_int(p.w);
    if ((d2 <= r2) && (p.z > 0.0f) && keyless(p.z, pi, zk[K - 1], ik[K - 1]))
        insert_topk(p.z, pi, d2, zk, ik, dk);
}

__global__ __launch_bounds__(256) void brute_kernel(
    const float* __restrict__ points, const float* __restrict__ w2v,
    const float* __restrict__ p2n, float* __restrict__ out) {
    int gid = blockIdx.x * 256 + threadIdx.x;   // 0..B*H*W-1
    int b = gid >> 14;
    int rem = gid & 16383;
    int h = rem >> 7, w = rem & 127;
    float px = 1.0f - (2.0f * (float)w + 1.0f) / 128.0f;
    float py = 1.0f - (2.0f * (float)h + 1.0f) / 128.0f;
    const float r2 = (float)(0.02 * 0.02);

    __shared__ float4 sh[256];

    float zk[K]; int ik[K]; float dk[K];
#pragma unroll
    for (int j = 0; j < K; ++j) { zk[j] = BIGF; ik[j] = 0x7fffffff; dk[j] = 0.0f; }

    for (int c = 0; c < N; c += 256) {
        __syncthreads();
        int n = c + threadIdx.x;
        float x = points[((size_t)b * N + n) * 3 + 0];
        float y = points[((size_t)b * N + n) * 3 + 1];
        float z = points[((size_t)b * N + n) * 3 + 2];
        float xn, yn, zn;
        transform_point(w2v, p2n, x, y, z, xn, yn, zn);
        sh[threadIdx.x] = make_float4(xn, yn, zn, __int_as_float(n));
        __syncthreads();
        for (int e = 0; e < 256; ++e)
            process_candidate(sh[e], px, py, r2, zk, ik, dk);
    }
    write_out(out, gid, zk, ik, dk);
}

extern "C" void kernel_launch(void* const* d_in, const int* in_sizes, int n_in,
                              void* d_out, int out_size, void* d_ws, size_t ws_size,
                              hipStream_t stream) {
    const float* points = (const float*)d_in[0];
    const float* w2v    = (const float*)d_in[1];
    const float* p2n    = (const float*)d_in[2];
    float* out = (float*)d_out;

    const size_t cnt_bytes = (size_t)TOTPIX * sizeof(int);            // 256 KB
    const size_t ent_off   = 1 << 20;                                 // 1 MB
    const size_t need = ent_off + (size_t)CAPP * TOTPIX * sizeof(float4); // ~33 MB

    if (ws_size >= need) {
        int* cnt = (int*)d_ws;
        float4* entries = (float4*)((char*)d_ws + ent_off);
        zero_cnt_kernel<<<TOTPIX / (256 * 4), 256, 0, stream>>>((int4*)cnt);
        bin_pixels_kernel<<<(B * N) / 128, 128, 0, stream>>>(points, w2v, p2n, cnt, entries);
        select_kernel<<<TOTPIX / 256, 256, 0, stream>>>(cnt, entries, out);
        (void)cnt_bytes;
    } else {
        brute_kernel<<<(B * H * W) / 256, 256, 0, stream>>>(points, w2v, p2n, out);
    }
}